// Round 1
// baseline (297.020 us; speedup 1.0000x reference)
//
#include <hip/hip_runtime.h>
#include <math.h>

// Problem constants (match reference)
constexpr int N_ROWS = 100000;   // outputSize
constexpr int D      = 128;      // feature dim
constexpr int B      = 128;      // batch
constexpr int KP1    = 4097;     // K+1
constexpr int TOTAL_PAIRS = B * KP1;            // 524,416
constexpr float INV_T = 1.0f / 0.07f;

// ---------------------------------------------------------------------------
// ws[0] = sum of unnormalized out_v1, ws[1] = sum of unnormalized out_v2
__global__ void init_ws_kernel(float* ws) {
    if (threadIdx.x < 2) ws[threadIdx.x] = 0.0f;
}

// ---------------------------------------------------------------------------
// One 32-lane group per (b,k) pair. Each lane loads a float4 of the gathered
// row from each bank (32 lanes x 16B = 512B = one full row, coalesced),
// dot against v1[b]/v2[b], butterfly-reduce within the 32-lane group,
// lane 0 computes exp and stores the unnormalized score. Per-block partial
// sums -> one atomicAdd per block per accumulator.
__global__ __launch_bounds__(256) void score_kernel(
    const float* __restrict__ v1, const float* __restrict__ v2,
    const int* __restrict__ idx,
    const float* __restrict__ mem1, const float* __restrict__ mem2,
    float* __restrict__ out,   // [0:TOTAL) = out_v1 unnorm, [TOTAL:2*TOTAL) = out_v2 unnorm
    float* __restrict__ sums)  // ws: 2 floats
{
    const int l   = threadIdx.x & 31;        // lane within 32-lane group
    const int grp = threadIdx.x >> 5;        // 0..7 groups per 256-thread block
    const int n_groups = gridDim.x * 8;
    int g = blockIdx.x * 8 + grp;

    const float4* __restrict__ m1 = (const float4*)mem1;
    const float4* __restrict__ m2 = (const float4*)mem2;
    const float4* __restrict__ a1p = (const float4*)v1;
    const float4* __restrict__ a2p = (const float4*)v2;

    float acc1 = 0.0f, acc2 = 0.0f;

    for (int p = g; p < TOTAL_PAIRS; p += n_groups) {
        int row = idx[p];
        unsigned b = (unsigned)p / (unsigned)KP1;   // compiler magic-mul

        float4 w1 = m1[(size_t)row * 32 + l];
        float4 w2 = m2[(size_t)row * 32 + l];
        float4 a1 = a1p[b * 32 + l];
        float4 a2 = a2p[b * 32 + l];

        // out_v1 uses memory_v2 . v1 ; out_v2 uses memory_v1 . v2
        float d1 = w2.x * a1.x + w2.y * a1.y + w2.z * a1.z + w2.w * a1.w;
        float d2 = w1.x * a2.x + w1.y * a2.y + w1.z * a2.z + w1.w * a2.w;

        // butterfly reduce within 32-lane group (xor masks <32 stay in-half)
        #pragma unroll
        for (int off = 16; off >= 1; off >>= 1) {
            d1 += __shfl_xor(d1, off);
            d2 += __shfl_xor(d2, off);
        }

        if (l == 0) {
            float e1 = __expf(d1 * INV_T);
            float e2 = __expf(d2 * INV_T);
            out[p]               = e1;
            out[TOTAL_PAIRS + p] = e2;
            acc1 += e1;
            acc2 += e2;
        }
    }

    // Block reduction: only lanes with l==0 (one per group) hold partials.
    __shared__ float s1[8], s2[8];
    if (l == 0) { s1[grp] = acc1; s2[grp] = acc2; }
    __syncthreads();
    if (threadIdx.x == 0) {
        float t1 = 0.0f, t2 = 0.0f;
        #pragma unroll
        for (int i = 0; i < 8; ++i) { t1 += s1[i]; t2 += s2[i]; }
        atomicAdd(&sums[0], t1);
        atomicAdd(&sums[1], t2);
    }
}

// ---------------------------------------------------------------------------
// out_v1 /= Z_v1, out_v2 /= Z_v2 where Z = (sum / TOTAL) * N
__global__ __launch_bounds__(256) void scale_kernel(
    float* __restrict__ out, const float* __restrict__ sums)
{
    int i = blockIdx.x * blockDim.x + threadIdx.x;
    if (i >= 2 * TOTAL_PAIRS) return;
    float s = (i < TOTAL_PAIRS) ? sums[0] : sums[1];
    float sc = (float)((double)TOTAL_PAIRS / ((double)s * (double)N_ROWS));
    out[i] *= sc;
}

// ---------------------------------------------------------------------------
// Pass-through copy of both memory banks into the output regions (float4).
__global__ __launch_bounds__(256) void copy_mem_kernel(
    const float4* __restrict__ m1, const float4* __restrict__ m2,
    float4* __restrict__ o1, float4* __restrict__ o2)
{
    const int n4 = N_ROWS * (D / 4);   // 3.2M float4 per bank
    for (int i = blockIdx.x * blockDim.x + threadIdx.x; i < n4;
         i += gridDim.x * blockDim.x) {
        o1[i] = m1[i];
        o2[i] = m2[i];
    }
}

// ---------------------------------------------------------------------------
// Overwrite rows y[b] with normalize(0.5*mem[y[b]] + 0.5*v[b]).
// One 64-thread block per (bank, b). Runs after copy_mem_kernel.
__global__ __launch_bounds__(64) void update_rows_kernel(
    const float* __restrict__ v1, const float* __restrict__ v2,
    const int* __restrict__ y,
    const float* __restrict__ mem1, const float* __restrict__ mem2,
    float* __restrict__ o1, float* __restrict__ o2)
{
    int b    = blockIdx.x & (B - 1);
    int bank = blockIdx.x >> 7;
    int lane = threadIdx.x;               // 0..63, float2 each -> 128 floats

    const float2* __restrict__ m = (const float2*)(bank ? mem2 : mem1);
    const float2* __restrict__ v = (const float2*)(bank ? v2 : v1);
    float2* __restrict__ o       = (float2*)(bank ? o2 : o1);

    int row = y[b];
    float2 mv = m[(size_t)row * 64 + lane];
    float2 vv = v[b * 64 + lane];
    float2 u;
    u.x = 0.5f * mv.x + 0.5f * vv.x;
    u.y = 0.5f * mv.y + 0.5f * vv.y;

    float ss = u.x * u.x + u.y * u.y;
    #pragma unroll
    for (int off = 32; off >= 1; off >>= 1)
        ss += __shfl_xor(ss, off);

    float inv = 1.0f / sqrtf(ss);
    float2 r; r.x = u.x * inv; r.y = u.y * inv;
    o[(size_t)row * 64 + lane] = r;
}

// ---------------------------------------------------------------------------
extern "C" void kernel_launch(void* const* d_in, const int* in_sizes, int n_in,
                              void* d_out, int out_size, void* d_ws, size_t ws_size,
                              hipStream_t stream) {
    const float* v1   = (const float*)d_in[0];
    const float* v2   = (const float*)d_in[1];
    const int*   idx  = (const int*)d_in[2];
    const int*   y    = (const int*)d_in[3];
    const float* mem1 = (const float*)d_in[4];
    const float* mem2 = (const float*)d_in[5];

    float* out = (float*)d_out;
    float* out_mem1 = out + 2 * (size_t)TOTAL_PAIRS;
    float* out_mem2 = out_mem1 + (size_t)N_ROWS * D;
    float* sums = (float*)d_ws;

    init_ws_kernel<<<1, 64, 0, stream>>>(sums);

    // 1024 blocks x 256 thr = 8192 groups; ~64 pairs per group
    score_kernel<<<1024, 256, 0, stream>>>(v1, v2, idx, mem1, mem2, out, sums);

    scale_kernel<<<(2 * TOTAL_PAIRS + 255) / 256, 256, 0, stream>>>(out, sums);

    copy_mem_kernel<<<2048, 256, 0, stream>>>(
        (const float4*)mem1, (const float4*)mem2,
        (float4*)out_mem1, (float4*)out_mem2);

    update_rows_kernel<<<2 * B, 64, 0, stream>>>(
        v1, v2, y, mem1, mem2, out_mem1, out_mem2);
}

// Round 2
// 287.513 us; speedup vs baseline: 1.0331x; 1.0331x over previous
//
#include <hip/hip_runtime.h>
#include <math.h>

// Problem constants (match reference)
constexpr int N_ROWS = 100000;   // outputSize
constexpr int D      = 128;      // feature dim
constexpr int B      = 128;      // batch
constexpr int KP1    = 4097;     // K+1
constexpr int TOTAL_PAIRS = B * KP1;            // 524,416
constexpr float INV_T = 1.0f / 0.07f;
constexpr int N4 = N_ROWS * (D / 4);            // float4 per bank: 3.2M

constexpr int SC_BLOCKS = 1024;  // score blocks (even blockIdx)
constexpr int CP_BLOCKS = 1024;  // copy  blocks (odd blockIdx)

// ---------------------------------------------------------------------------
__global__ void init_ws_kernel(float* ws) {
    if (threadIdx.x < 2) ws[threadIdx.x] = 0.0f;
}

__device__ __forceinline__ float dot4(float4 a, float4 b) {
    return a.x * b.x + a.y * b.y + a.z * b.z + a.w * b.w;
}

__device__ __forceinline__ float red32(float v) {
    #pragma unroll
    for (int off = 16; off >= 1; off >>= 1) v += __shfl_xor(v, off);
    return v;
}

// ---------------------------------------------------------------------------
// Even blocks: score. One 32-lane group per (b, k-stripe); each group owns a
// fixed b (v-vectors stay in registers), strides over k, unrolled x2 so 4
// gathered-row loads are in flight. Odd blocks: stream-copy both memory
// banks to the output regions — rides under the score phase's idle HBM BW.
__global__ __launch_bounds__(256) void mega_kernel(
    const float* __restrict__ v1, const float* __restrict__ v2,
    const int* __restrict__ idx,
    const float* __restrict__ mem1, const float* __restrict__ mem2,
    float* __restrict__ out,          // [0:T) unnorm out_v1, [T:2T) unnorm out_v2
    float* __restrict__ sums,         // ws: 2 floats
    float4* __restrict__ o1, float4* __restrict__ o2)
{
    if (blockIdx.x & 1) {
        // ---- copy half ----
        int cid = blockIdx.x >> 1;                    // 0..CP_BLOCKS-1
        const float4* __restrict__ m1 = (const float4*)mem1;
        const float4* __restrict__ m2 = (const float4*)mem2;
        int tid = cid * 256 + threadIdx.x;
        int stride = CP_BLOCKS * 256;
        for (int i = tid; i < N4; i += stride) {
            o1[i] = m1[i];
            o2[i] = m2[i];
        }
        return;
    }

    // ---- score half ----
    const int sid = blockIdx.x >> 1;                  // 0..SC_BLOCKS-1
    const int l   = threadIdx.x & 31;                 // lane in 32-lane group
    const int grp = threadIdx.x >> 5;                 // 0..7
    const int g   = sid * 8 + grp;                    // 0..8191
    const int b   = g >> 6;                           // 64 groups per b
    const int gk  = g & 63;

    const float4* __restrict__ m1 = (const float4*)mem1;
    const float4* __restrict__ m2 = (const float4*)mem2;
    const float4 a1 = ((const float4*)v1)[b * 32 + l];
    const float4 a2 = ((const float4*)v2)[b * 32 + l];
    const int base = b * KP1;

    float acc1 = 0.0f, acc2 = 0.0f;
    int k = gk;
    // unrolled x2: pairs (base+k) and (base+k+64)
    for (; k + 64 < KP1; k += 128) {
        int p0 = base + k, p1 = base + k + 64;
        int r0 = idx[p0], r1 = idx[p1];
        float4 w10 = m1[(size_t)r0 * 32 + l];
        float4 w20 = m2[(size_t)r0 * 32 + l];
        float4 w11 = m1[(size_t)r1 * 32 + l];
        float4 w21 = m2[(size_t)r1 * 32 + l];

        // out_v1 = mem2 . v1 ; out_v2 = mem1 . v2
        float d10 = red32(dot4(w20, a1));
        float d20 = red32(dot4(w10, a2));
        float d11 = red32(dot4(w21, a1));
        float d21 = red32(dot4(w11, a2));

        if (l == 0) {
            float e10 = __expf(d10 * INV_T);
            float e20 = __expf(d20 * INV_T);
            float e11 = __expf(d11 * INV_T);
            float e21 = __expf(d21 * INV_T);
            out[p0]               = e10;
            out[TOTAL_PAIRS + p0] = e20;
            out[p1]               = e11;
            out[TOTAL_PAIRS + p1] = e21;
            acc1 += e10 + e11;
            acc2 += e20 + e21;
        }
    }
    // tail (at most one k)
    for (; k < KP1; k += 64) {
        int p0 = base + k;
        int r0 = idx[p0];
        float4 w10 = m1[(size_t)r0 * 32 + l];
        float4 w20 = m2[(size_t)r0 * 32 + l];
        float d10 = red32(dot4(w20, a1));
        float d20 = red32(dot4(w10, a2));
        if (l == 0) {
            float e10 = __expf(d10 * INV_T);
            float e20 = __expf(d20 * INV_T);
            out[p0]               = e10;
            out[TOTAL_PAIRS + p0] = e20;
            acc1 += e10;
            acc2 += e20;
        }
    }

    // block reduction -> one atomic per block per accumulator
    __shared__ float s1[8], s2[8];
    if (l == 0) { s1[grp] = acc1; s2[grp] = acc2; }
    __syncthreads();
    if (threadIdx.x == 0) {
        float t1 = 0.0f, t2 = 0.0f;
        #pragma unroll
        for (int i = 0; i < 8; ++i) { t1 += s1[i]; t2 += s2[i]; }
        atomicAdd(&sums[0], t1);
        atomicAdd(&sums[1], t2);
    }
}

// ---------------------------------------------------------------------------
// Scale scores by 1/Z and overwrite the y-rows of the copied banks with
// normalize(0.5*mem + 0.5*v). Runs after mega_kernel (stream-ordered).
__global__ __launch_bounds__(256) void finish_kernel(
    float* __restrict__ out, const float* __restrict__ sums,
    const float* __restrict__ v1, const float* __restrict__ v2,
    const int* __restrict__ y,
    const float* __restrict__ mem1, const float* __restrict__ mem2,
    float* __restrict__ o1, float* __restrict__ o2)
{
    // row updates: blocks 0..255, wave 0 of each
    if (blockIdx.x < 2 * B && threadIdx.x < 64) {
        int b    = blockIdx.x & (B - 1);
        int bank = blockIdx.x >> 7;
        int lane = threadIdx.x;
        const float2* __restrict__ m = (const float2*)(bank ? mem2 : mem1);
        const float2* __restrict__ v = (const float2*)(bank ? v2 : v1);
        float2* __restrict__ o       = (float2*)(bank ? o2 : o1);
        int row = y[b];
        float2 mv = m[(size_t)row * 64 + lane];
        float2 vv = v[b * 64 + lane];
        float2 u;
        u.x = 0.5f * mv.x + 0.5f * vv.x;
        u.y = 0.5f * mv.y + 0.5f * vv.y;
        float ss = u.x * u.x + u.y * u.y;
        #pragma unroll
        for (int off = 32; off >= 1; off >>= 1) ss += __shfl_xor(ss, off);
        float inv = 1.0f / sqrtf(ss);
        float2 r; r.x = u.x * inv; r.y = u.y * inv;
        o[(size_t)row * 64 + lane] = r;
    }

    // scale: grid-stride over both score regions
    float sc1 = (float)((double)TOTAL_PAIRS / ((double)sums[0] * (double)N_ROWS));
    float sc2 = (float)((double)TOTAL_PAIRS / ((double)sums[1] * (double)N_ROWS));
    int stride = gridDim.x * blockDim.x;
    for (int i = blockIdx.x * blockDim.x + threadIdx.x; i < 2 * TOTAL_PAIRS;
         i += stride) {
        out[i] *= (i < TOTAL_PAIRS) ? sc1 : sc2;
    }
}

// ---------------------------------------------------------------------------
extern "C" void kernel_launch(void* const* d_in, const int* in_sizes, int n_in,
                              void* d_out, int out_size, void* d_ws, size_t ws_size,
                              hipStream_t stream) {
    const float* v1   = (const float*)d_in[0];
    const float* v2   = (const float*)d_in[1];
    const int*   idx  = (const int*)d_in[2];
    const int*   y    = (const int*)d_in[3];
    const float* mem1 = (const float*)d_in[4];
    const float* mem2 = (const float*)d_in[5];

    float* out = (float*)d_out;
    float* out_mem1 = out + 2 * (size_t)TOTAL_PAIRS;
    float* out_mem2 = out_mem1 + (size_t)N_ROWS * D;
    float* sums = (float*)d_ws;

    init_ws_kernel<<<1, 64, 0, stream>>>(sums);

    mega_kernel<<<SC_BLOCKS + CP_BLOCKS, 256, 0, stream>>>(
        v1, v2, idx, mem1, mem2, out, sums,
        (float4*)out_mem1, (float4*)out_mem2);

    finish_kernel<<<1024, 256, 0, stream>>>(
        out, sums, v1, v2, y, mem1, mem2, out_mem1, out_mem2);
}